// Round 18
// baseline (422.838 us; speedup 1.0000x reference)
//
#include <hip/hip_runtime.h>
#include <hip/hip_bf16.h>

// Established facts (R3-R34): d_in = setup_inputs() dict order; floats fp32;
// edges int32; output fp32 [20000,128]. R34 = 408.2us BEST. PULL NEAR-
// ROOFLINE ~87.5us x2. build_gemm 113us exposed scatter ~95-105us standalone
// (VALU 17%, HBM 10%, occ 63% -> 1.92M device atomics are the cost). Two
// models: same-address serialization (16 RMW chains/counter) vs per-channel
// atomic throughput (~30cy x 960K/128ch ~ 94us, distribution-invariant).
// This round (discriminating experiment): 2-way sub-bucket scatter (s=k&1,
// 2 sub-counters + 2x32 slot halves per bucket; P(overflow)<1e-9) -- same
// atomic count, half the same-address chain depth. Pull walks two segments
// via cndmask index; order already race-nondeterministic. If unchanged ->
// channel-bound -> scatter at atomic roofline.
#define NN 20000
#define RR 3
#define EE 320000
#define FD 128
#define AH 32
#define NP1 (NN + 1)
#define NEG_SLOPE 0.2f
#define BKN 256         // logit buckets per relation
#define NW 4            // waves per block in pull_fused
#define NPW2 8          // nodes per wave
#define NPB (NW * NPW2) // 32 nodes per block
#define LZP (FD + 2)    // padded LDS row: stride 130 (bank-conflict-free)
#define CAP 64          // bucket capacity per (relation, node)
#define HCAP 32         // half-bucket capacity (2-way sub-buckets)
#define GB2 (NN / 32)   // 625 gemm blocks per relation in build_gemm

__device__ __forceinline__ int clamp_idx(int v) {
  v = v < 0 ? 0 : v;
  return v < NN ? v : NN - 1;
}
// leaky_relu(e) == max(e, 0.2*e) for all e (0.2e > e when e < 0)
__device__ __forceinline__ float leaky_exp(float e) {
  return __expf(fmaxf(e, NEG_SLOPE * e));
}
__device__ __forceinline__ float bf2f(unsigned short u) {
  union { unsigned int i; float f; } c;
  c.i = ((unsigned int)u) << 16;
  return c.f;
}
// fp32 -> bf16 with round-to-nearest-even (values are finite, |v| ~ O(1))
__device__ __forceinline__ unsigned short f2bf(float v) {
  union { float f; unsigned int i; } c;
  c.f = v;
  const unsigned int u = c.i;
  return (unsigned short)((u + 0x7fffu + ((u >> 16) & 1u)) >> 16);
}

// ---------------------------------------------------------------------------
// build_gemm: FAT kernel. Blocks [0, RR*GB2) run layer-1 gemm (4 waves x 8
// nodes; R31-proven per-wave math -> bit-identical fb/el/er). Blocks
// [RR*GB2, +3750) run the 2-way sub-bucket scatter: s = k&1, sub-counter
// len2[(r*NN+dst)*2+s], slot = s*HCAP + pos. Roles touch disjoint data.
// ---------------------------------------------------------------------------
__global__ void __launch_bounds__(256, 2) build_gemm(
    const int* __restrict__ edg,
    int* __restrict__ len2,                   // [3,NN,2]
    int* __restrict__ adj,                    // [3,NN,CAP]
    const float* __restrict__ hin,            // [N,128]
    const float* __restrict__ W,              // [3,128,128]
    const float* __restrict__ al,             // [3,128]
    const float* __restrict__ ar,             // [3,128]
    unsigned short* __restrict__ fb,          // [3,N,128] bf16
    float* __restrict__ el,                   // [3,N,2]
    float* __restrict__ er) {
  __shared__ float lh[32 * FD];  // 16 KB (gemm role only)
  const int gemmBlocks = RR * GB2;  // 1875
  const int t = threadIdx.x;

  if (blockIdx.x >= gemmBlocks) {
    // ---------------- scatter role (2-way sub-buckets) ---------------------
    const int idx = (blockIdx.x - gemmBlocks) * 256 + t;
    if (idx >= RR * EE) return;
    const int r = idx / EE, k = idx - r * EE;
    const int src = clamp_idx(edg[(size_t)r * 2 * EE + k]);
    const int dst = clamp_idx(edg[(size_t)r * 2 * EE + EE + k]);
    const int s = k & 1;
    const int pos = atomicAdd(&len2[((size_t)r * NN + dst) * 2 + s], 1);
    if (pos < HCAP)
      adj[((size_t)r * NN + dst) * CAP + s * HCAP + pos] = src;
    return;
  }

  // ---------------- gemm role (R31 per-wave math, 4 waves) -----------------
  const int r = blockIdx.x / GB2;
  const int n0 = (blockIdx.x - r * GB2) * 32;
  const int wv = t >> 6;       // wave 0..3
  const int j = t & 63;        // lane

  {
    const float4* s4 = (const float4*)&hin[(size_t)n0 * FD];
    float4* d4 = (float4*)lh;
#pragma unroll
    for (int p = 0; p < 4; ++p) d4[t + 256 * p] = s4[t + 256 * p];
  }
  __syncthreads();

  const float* Wr = W + (size_t)r * FD * FD;
  const float* lhw = lh + wv * 8 * FD;  // this wave's 8 nodes
  float acc0[8], acc1[8];
#pragma unroll
  for (int i = 0; i < 8; ++i) { acc0[i] = 0.f; acc1[i] = 0.f; }

  for (int k4 = 0; k4 < FD; k4 += 4) {
    const float wa0 = Wr[(size_t)(k4 + 0) * FD + j];
    const float wb0 = Wr[(size_t)(k4 + 0) * FD + j + 64];
    const float wa1 = Wr[(size_t)(k4 + 1) * FD + j];
    const float wb1 = Wr[(size_t)(k4 + 1) * FD + j + 64];
    const float wa2 = Wr[(size_t)(k4 + 2) * FD + j];
    const float wb2 = Wr[(size_t)(k4 + 2) * FD + j + 64];
    const float wa3 = Wr[(size_t)(k4 + 3) * FD + j];
    const float wb3 = Wr[(size_t)(k4 + 3) * FD + j + 64];
#pragma unroll
    for (int i = 0; i < 8; ++i) {
      const float4 h4 = *(const float4*)&lhw[i * FD + k4];
      acc0[i] = fmaf(h4.x, wa0, fmaf(h4.y, wa1, fmaf(h4.z, wa2, fmaf(h4.w, wa3, acc0[i]))));
      acc1[i] = fmaf(h4.x, wb0, fmaf(h4.y, wb1, fmaf(h4.z, wb2, fmaf(h4.w, wb3, acc1[i]))));
    }
  }

  const float al0 = al[r * FD + j];
  const float al1v = al[r * FD + j + 64];
  const float ar0 = ar[r * FD + j];
  const float ar1v = ar[r * FD + j + 64];

#pragma unroll
  for (int i = 0; i < 8; ++i) {
    const int node = n0 + wv * 8 + i;
    const size_t row = ((size_t)r * NN + node) * FD;
    fb[row + j] = f2bf(acc0[i]);
    fb[row + j + 64] = f2bf(acc1[i]);
    float e0 = acc0[i] * al0;
    float e1 = acc1[i] * al1v;
    float u0 = acc0[i] * ar0;
    float u1 = acc1[i] * ar1v;
#pragma unroll
    for (int off = 32; off > 0; off >>= 1) {
      e0 += __shfl_down(e0, off, 64);
      e1 += __shfl_down(e1, off, 64);
      u0 += __shfl_down(u0, off, 64);
      u1 += __shfl_down(u1, off, 64);
    }
    if (j == 0) {
      const size_t base = ((size_t)r * NN + node) * 2;
      el[base + 0] = e0;
      el[base + 1] = e1;
      er[base + 0] = u0;
      er[base + 1] = u1;
    }
  }
}

// ---------------------------------------------------------------------------
// gemm_mix (R33-proven): layer-2 gemm with L1 combine fused into staging.
// ---------------------------------------------------------------------------
#define BN 16
__global__ void __launch_bounds__(128, 2) gemm_mix(
    const float* __restrict__ z,              // [3,N,128] layer-1 outputs
    const float* __restrict__ bk,             // [3,BKN] logit buckets
    const float* __restrict__ W,              // [3,128,128]
    const float* __restrict__ al,             // [3,128]
    const float* __restrict__ ar,             // [3,128]
    unsigned short* __restrict__ fb,          // [3,N,128] bf16
    float* __restrict__ el,                   // [3,N,2]
    float* __restrict__ er) {
  __shared__ float lh[BN * FD];  // 8 KB
  __shared__ float red[128];
  __shared__ float betas[4];
  const int blocksPerRel = NN / BN;  // 1250
  const int r = blockIdx.x / blocksPerRel;
  const int n0 = (blockIdx.x % blocksPerRel) * BN;
  const int t = threadIdx.x;   // 0..127
  const int wv = t >> 6;       // wave 0/1
  const int j = t & 63;        // lane

  // ---- beta from buckets (matches combine_bk's reduction + softmax) ----
  float tot[RR];
#pragma unroll
  for (int r2 = 0; r2 < RR; ++r2) {
    red[t] = bk[r2 * BKN + t] + bk[r2 * BKN + t + 128];
    __syncthreads();
    for (int off = 64; off > 0; off >>= 1) {
      if (t < off) red[t] += red[t + off];
      __syncthreads();
    }
    tot[r2] = red[0];
    __syncthreads();
  }
  if (t == 0) {
    const float w0 = tot[0] * (1.f / NN);
    const float w1 = tot[1] * (1.f / NN);
    const float w2 = tot[2] * (1.f / NN);
    const float mx = fmaxf(w0, fmaxf(w1, w2));
    const float e0 = __expf(w0 - mx), e1 = __expf(w1 - mx), e2 = __expf(w2 - mx);
    const float inv = 1.f / (e0 + e1 + e2);
    betas[0] = e0 * inv; betas[1] = e1 * inv; betas[2] = e2 * inv;
  }
  __syncthreads();
  const float b0 = betas[0], b1 = betas[1], b2 = betas[2];

  // ---- stage mixed hmid tile: 16 nodes x 128 cols = 512 float4 ----
  {
    const float4* z40 = (const float4*)&z[(size_t)n0 * FD];
    const float4* z41 = (const float4*)&z[(size_t)NN * FD + (size_t)n0 * FD];
    const float4* z42 = (const float4*)&z[2 * (size_t)NN * FD + (size_t)n0 * FD];
    float4* d4 = (float4*)lh;
#pragma unroll
    for (int p = 0; p < 4; ++p) {
      const int m = t + 128 * p;
      const float4 a = z40[m];
      const float4 bq = z41[m];
      const float4 c = z42[m];
      float4 o;
      o.x = b0 * a.x + b1 * bq.x + b2 * c.x;
      o.y = b0 * a.y + b1 * bq.y + b2 * c.y;
      o.z = b0 * a.z + b1 * bq.z + b2 * c.z;
      o.w = b0 * a.w + b1 * bq.w + b2 * c.w;
      d4[m] = o;
    }
  }
  __syncthreads();

  const float* Wr = W + (size_t)r * FD * FD;
  const float* lhw = lh + wv * 8 * FD;  // this wave's 8 nodes
  float acc0[8], acc1[8];
#pragma unroll
  for (int i = 0; i < 8; ++i) { acc0[i] = 0.f; acc1[i] = 0.f; }

  for (int k4 = 0; k4 < FD; k4 += 4) {
    const float wa0 = Wr[(size_t)(k4 + 0) * FD + j];
    const float wb0 = Wr[(size_t)(k4 + 0) * FD + j + 64];
    const float wa1 = Wr[(size_t)(k4 + 1) * FD + j];
    const float wb1 = Wr[(size_t)(k4 + 1) * FD + j + 64];
    const float wa2 = Wr[(size_t)(k4 + 2) * FD + j];
    const float wb2 = Wr[(size_t)(k4 + 2) * FD + j + 64];
    const float wa3 = Wr[(size_t)(k4 + 3) * FD + j];
    const float wb3 = Wr[(size_t)(k4 + 3) * FD + j + 64];
#pragma unroll
    for (int i = 0; i < 8; ++i) {
      const float4 h4 = *(const float4*)&lhw[i * FD + k4];
      acc0[i] = fmaf(h4.x, wa0, fmaf(h4.y, wa1, fmaf(h4.z, wa2, fmaf(h4.w, wa3, acc0[i]))));
      acc1[i] = fmaf(h4.x, wb0, fmaf(h4.y, wb1, fmaf(h4.z, wb2, fmaf(h4.w, wb3, acc1[i]))));
    }
  }

  const float al0 = al[r * FD + j];
  const float al1v = al[r * FD + j + 64];
  const float ar0 = ar[r * FD + j];
  const float ar1v = ar[r * FD + j + 64];

#pragma unroll
  for (int i = 0; i < 8; ++i) {
    const int node = n0 + wv * 8 + i;
    const size_t row = ((size_t)r * NN + node) * FD;
    fb[row + j] = f2bf(acc0[i]);
    fb[row + j + 64] = f2bf(acc1[i]);
    float e0 = acc0[i] * al0;
    float e1 = acc1[i] * al1v;
    float u0 = acc0[i] * ar0;
    float u1 = acc1[i] * ar1v;
#pragma unroll
    for (int off = 32; off > 0; off >>= 1) {
      e0 += __shfl_down(e0, off, 64);
      e1 += __shfl_down(e1, off, 64);
      u0 += __shfl_down(u0, off, 64);
      u1 += __shfl_down(u1, off, 64);
    }
    if (j == 0) {
      const size_t base = ((size_t)r * NN + node) * 2;
      el[base + 0] = e0;
      el[base + 1] = e1;
      er[base + 0] = u0;
      er[base + 1] = u1;
    }
  }
}

// ---------------------------------------------------------------------------
// pull_fused v6: R34-proven structure; bucket is now 2 sub-segments
// [0,l0) and [HCAP, HCAP+l1). Lanes 0-7 map loop index k -> slot via one
// cndmask: kk = k < l0 ? k : HCAP + k - l0; deg = l0 + l1. Gather math,
// LDS layout, MLP, bucket-atomic logits all unchanged.
// ---------------------------------------------------------------------------
__global__ void __launch_bounds__(256, 4) pull_fused(
    const int* __restrict__ len2,     // [3,NN,2]
    const int* __restrict__ adj,      // [3,NN,CAP]
    const float* __restrict__ el,     // [3,N,2]
    const float* __restrict__ er,
    const unsigned short* __restrict__ fb,  // [3,N,128] bf16
    const float* __restrict__ b,      // [3,128]
    int do_relu,
    const float* __restrict__ aw1,    // [128,32]
    const float* __restrict__ ab1,    // [32]
    const float* __restrict__ aw2,    // [32]
    float* __restrict__ z,            // [3,N,128]
    float* __restrict__ bucket) {     // [3,BKN]
  __shared__ float lz[NPB][LZP];  // 32 x 130 floats = 16.6 KB
  const int t = threadIdx.x;
  const int wave = t >> 6;
  const int l = t & 63;
  const int g = l & 7;                     // node group within wave
  const int bpr = NN / NPB;  // 625
  const int r = blockIdx.x / bpr;
  const int nb = (blockIdx.x - r * bpr) * NPB;
  const int widx = wave * NPW2 + g;        // node index within block 0..31
  const int node = nb + widx;
  const int h = (l >> 3) & 1;
  const int q = l >> 4;                    // 0..3
  const int rn = r * NN + node;
  const int* ln2 = len2 + (size_t)r * NN * 2;
  const int* ad = adj + (size_t)r * NN * CAP;
  const float2* el2 = (const float2*)(el + (size_t)r * NN * 2);
  const unsigned int* fru = (const unsigned int*)(fb + (size_t)r * NN * FD);
  const int l0 = min(ln2[node * 2 + 0], HCAP);
  const int l1 = min(ln2[node * 2 + 1], HCAP);
  const int deg = l0 + l1;
  const size_t s0 = (size_t)node * CAP;
  const float ern = er[(size_t)rn * 2 + h];

  float2 acc[8];
#pragma unroll
  for (int i = 0; i < 8; ++i) acc[i] = make_float2(0.f, 0.f);
  float den = 0.f;

  // max degree over the 8 nodes of this wave (node id depends only on l&7)
  int md = deg;
  md = max(md, __shfl_xor(md, 1, 64));
  md = max(md, __shfl_xor(md, 2, 64));
  md = max(md, __shfl_xor(md, 4, 64));

  for (int k = 0; k < md; ++k) {
    // lanes 0..7 load adj + el2 for their group (8 addresses instead of 64)
    int srcv = 0;
    float2 e2v = make_float2(0.f, 0.f);
    if (l < 8 && k < deg) {           // lane l<8 has g==l -> own l0/deg
      const int kk = (k < l0) ? k : (HCAP + k - l0);
      srcv = ad[s0 + kk];
      e2v = el2[srcv];
    }
    const int src = __shfl(srcv, g, 64);
    const float ex = __shfl(e2v.x, g, 64);
    const float ey = __shfl(e2v.y, g, 64);
    if (k < deg) {
      const float w = leaky_exp((h ? ey : ex) + ern);
      den += w;
      const uint4* frow = (const uint4*)(fru + (src << 6) + (h << 5) + (q << 3));
      const uint4 fa = frow[0];
      const uint4 fbv = frow[1];
      acc[0].x += w * bf2f((unsigned short)(fa.x & 0xffff));
      acc[0].y += w * bf2f((unsigned short)(fa.x >> 16));
      acc[1].x += w * bf2f((unsigned short)(fa.y & 0xffff));
      acc[1].y += w * bf2f((unsigned short)(fa.y >> 16));
      acc[2].x += w * bf2f((unsigned short)(fa.z & 0xffff));
      acc[2].y += w * bf2f((unsigned short)(fa.z >> 16));
      acc[3].x += w * bf2f((unsigned short)(fa.w & 0xffff));
      acc[3].y += w * bf2f((unsigned short)(fa.w >> 16));
      acc[4].x += w * bf2f((unsigned short)(fbv.x & 0xffff));
      acc[4].y += w * bf2f((unsigned short)(fbv.x >> 16));
      acc[5].x += w * bf2f((unsigned short)(fbv.y & 0xffff));
      acc[5].y += w * bf2f((unsigned short)(fbv.y >> 16));
      acc[6].x += w * bf2f((unsigned short)(fbv.z & 0xffff));
      acc[6].y += w * bf2f((unsigned short)(fbv.z >> 16));
      acc[7].x += w * bf2f((unsigned short)(fbv.w & 0xffff));
      acc[7].y += w * bf2f((unsigned short)(fbv.w >> 16));
    }
  }

  const float inv = 1.f / fmaxf(den, 1e-9f);
  const int cbase = h * 64 + q * 16;
  const float* bb = b + r * FD + cbase;
  float* zr = z + (size_t)rn * FD + cbase;
#pragma unroll
  for (int cp = 0; cp < 8; ++cp) {
    float vx = acc[cp].x * inv + bb[2 * cp];
    float vy = acc[cp].y * inv + bb[2 * cp + 1];
    if (do_relu) { vx = fmaxf(vx, 0.f); vy = fmaxf(vy, 0.f); }
    ((float2*)zr)[cp] = make_float2(vx, vy);
    lz[widx][cbase + 2 * cp] = vx;
    lz[widx][cbase + 2 * cp + 1] = vy;
  }
  __syncthreads();

  // ---- fused semantic-attention logit for the block's 32 nodes ----
  // 8 threads per node; thread i owns cols i, i+8, i+16, i+24.
  const int mnode = t >> 3;   // 0..31
  const int i = t & 7;
  float a0 = ab1[i], a1 = ab1[i + 8], a2 = ab1[i + 16], a3 = ab1[i + 24];
  const float* aw1i = aw1 + i;
  for (int k = 0; k < FD; ++k) {
    const float zv = lz[mnode][k];
    const float* a = aw1i + (size_t)k * AH;
    a0 = fmaf(zv, a[0], a0);
    a1 = fmaf(zv, a[8], a1);
    a2 = fmaf(zv, a[16], a2);
    a3 = fmaf(zv, a[24], a3);
  }
  float part = tanhf(a0) * aw2[i] + tanhf(a1) * aw2[i + 8] +
               tanhf(a2) * aw2[i + 16] + tanhf(a3) * aw2[i + 24];
  part += __shfl_down(part, 4, 64);
  part += __shfl_down(part, 2, 64);
  part += __shfl_down(part, 1, 64);
  if (i == 0)
    atomicAdd(&bucket[r * BKN + ((nb + mnode) & (BKN - 1))], part);
}

// grid-strided combine; reduces the 3*BKN logit buckets in-block and applies
// the beta softmax inline (R19/R24-proven)
__global__ void combine_bk(const float* __restrict__ z,
                           const float* __restrict__ bk,  // [3,BKN]
                           float* __restrict__ out) {
  __shared__ float p[256];
  __shared__ float beta[3];
  const int t = threadIdx.x;
  float tot[RR];
#pragma unroll
  for (int r = 0; r < RR; ++r) {
    p[t] = bk[r * BKN + t];
    __syncthreads();
    for (int off = 128; off > 0; off >>= 1) {
      if (t < off) p[t] += p[t + off];
      __syncthreads();
    }
    tot[r] = p[0];
    __syncthreads();
  }
  if (t == 0) {
    const float w0 = tot[0] * (1.f / NN);
    const float w1 = tot[1] * (1.f / NN);
    const float w2 = tot[2] * (1.f / NN);
    const float mx = fmaxf(w0, fmaxf(w1, w2));
    const float e0 = __expf(w0 - mx), e1 = __expf(w1 - mx), e2 = __expf(w2 - mx);
    const float inv = 1.f / (e0 + e1 + e2);
    beta[0] = e0 * inv; beta[1] = e1 * inv; beta[2] = e2 * inv;
  }
  __syncthreads();
  const float b0 = beta[0], b1 = beta[1], b2 = beta[2];
  for (int idx = blockIdx.x * 256 + t; idx < NN * FD; idx += gridDim.x * 256)
    out[idx] = b0 * z[idx] + b1 * z[(size_t)NN * FD + idx] +
               b2 * z[2 * (size_t)NN * FD + idx];
}

// ------------------- fallback kernels (R10 CSR path, proven) ----------------
__global__ void csr_count(const int* __restrict__ edg, int* __restrict__ cnt) {
  const int idx = blockIdx.x * blockDim.x + threadIdx.x;
  if (idx >= RR * EE) return;
  const int r = idx / EE, k = idx - r * EE;
  const int dst = clamp_idx(edg[(size_t)r * 2 * EE + EE + k]);
  atomicAdd(&cnt[r * NN + dst], 1);
}

__global__ void csr_scan(const int* __restrict__ cnt, int* __restrict__ starts,
                         int* __restrict__ cursor) {
  __shared__ int part[256];
  const int r = blockIdx.x, t = threadIdx.x;
  const int CH = (NN + 255) / 256;  // 79
  const int lo = t * CH, hi = min(lo + CH, NN);
  int s = 0;
  for (int i = lo; i < hi; ++i) s += cnt[r * NN + i];
  part[t] = s;
  __syncthreads();
  for (int off = 1; off < 256; off <<= 1) {
    const int x = part[t];
    const int y = (t >= off) ? part[t - off] : 0;
    __syncthreads();
    part[t] = x + y;
    __syncthreads();
  }
  int run = (t == 0) ? 0 : part[t - 1];
  for (int i = lo; i < hi; ++i) {
    starts[r * NP1 + i] = run;
    cursor[r * NP1 + i] = run;
    run += cnt[r * NN + i];
  }
  if (t == 255) starts[r * NP1 + NN] = run;
}

__global__ void csr_scatter(const int* __restrict__ edg, int* __restrict__ cursor,
                            int* __restrict__ csrsrc) {
  const int idx = blockIdx.x * blockDim.x + threadIdx.x;
  if (idx >= RR * EE) return;
  const int r = idx / EE, k = idx - r * EE;
  const int src = clamp_idx(edg[(size_t)r * 2 * EE + k]);
  const int dst = clamp_idx(edg[(size_t)r * 2 * EE + EE + k]);
  const int pos = atomicAdd(&cursor[r * NP1 + dst], 1);
  csrsrc[(size_t)r * EE + pos] = src;
}

__global__ void reduce_beta(const float* __restrict__ wv, float* __restrict__ S) {
  __shared__ float p[256];
  const int t = threadIdx.x;
  float tot[RR];
  for (int r = 0; r < RR; ++r) {
    float s = 0.f;
    for (int n = t; n < NN; n += 256) s += wv[(size_t)r * NN + n];
    p[t] = s;
    __syncthreads();
    for (int off = 128; off > 0; off >>= 1) {
      if (t < off) p[t] += p[t + off];
      __syncthreads();
    }
    tot[r] = p[0];
    __syncthreads();
  }
  if (t == 0) {
    S[0] = tot[0]; S[1] = tot[1]; S[2] = tot[2];
    float w0 = tot[0] / (float)NN, w1 = tot[1] / (float)NN, w2 = tot[2] / (float)NN;
    float mx = fmaxf(w0, fmaxf(w1, w2));
    float e0 = __expf(w0 - mx), e1 = __expf(w1 - mx), e2 = __expf(w2 - mx);
    float inv = 1.f / (e0 + e1 + e2);
    S[4] = e0 * inv; S[5] = e1 * inv; S[6] = e2 * inv;
  }
}

__global__ void combine_f32(const float* __restrict__ z,
                            const float* __restrict__ S,
                            float* __restrict__ out) {
  const int idx = blockIdx.x * blockDim.x + threadIdx.x;
  if (idx >= NN * FD) return;
  out[idx] = S[4] * z[idx] + S[5] * z[(size_t)NN * FD + idx] +
             S[6] * z[2 * (size_t)NN * FD + idx];
}

__global__ void gemm_el_er(const float* __restrict__ hin,
                           const float* __restrict__ W,
                           const float* __restrict__ al,
                           const float* __restrict__ ar,
                           float* __restrict__ f,
                           float* __restrict__ el,
                           float* __restrict__ er) {
  const int B8 = 8;
  __shared__ float lh[B8 * FD];
  const int j = threadIdx.x;
  const int n0 = blockIdx.x * B8;
#pragma unroll
  for (int i = 0; i < B8; ++i)
    lh[i * FD + j] = hin[(size_t)(n0 + i) * FD + j];
  __syncthreads();
  float acc[B8];
#pragma unroll
  for (int i = 0; i < B8; ++i) acc[i] = 0.f;
  for (int k = 0; k < FD; ++k) {
    const float w = W[(size_t)k * FD + j];
#pragma unroll
    for (int i = 0; i < B8; ++i) acc[i] += lh[i * FD + k] * w;
  }
  const float alv = al[j];
  const float arv = ar[j];
#pragma unroll
  for (int i = 0; i < B8; ++i) f[(size_t)(n0 + i) * FD + j] = acc[i];
  __syncthreads();
#pragma unroll
  for (int i = 0; i < B8; ++i) lh[i * FD + j] = acc[i] * alv;
  __syncthreads();
  if (j < B8 * 2) {
    const int i = j >> 1, h = j & 1;
    const float* p = &lh[i * FD + h * 64];
    float s = 0.f;
    for (int d = 0; d < 64; ++d) s += p[d];
    el[(size_t)(n0 + i) * 2 + h] = s;
  }
  __syncthreads();
#pragma unroll
  for (int i = 0; i < B8; ++i) lh[i * FD + j] = acc[i] * arv;
  __syncthreads();
  if (j < B8 * 2) {
    const int i = j >> 1, h = j & 1;
    const float* p = &lh[i * FD + h * 64];
    float s = 0.f;
    for (int d = 0; d < 64; ++d) s += p[d];
    er[(size_t)(n0 + i) * 2 + h] = s;
  }
}

__global__ void pull_aggr(const int* __restrict__ starts,
                          const int* __restrict__ csrsrc,
                          const float* __restrict__ el,
                          const float* __restrict__ er,
                          const float* __restrict__ f,
                          const float* __restrict__ b,
                          int do_relu,
                          float* __restrict__ z) {
  const int n = blockIdx.x;
  const int j = threadIdx.x;
  const int h = j >> 6;
  const int s0 = starts[n], s1 = starts[n + 1];
  const float ern = er[(size_t)n * 2 + h];
  float acc = 0.f, den = 0.f;
  for (int p = s0; p < s1; ++p) {
    const int src = csrsrc[p];
    const float w = leaky_exp(el[(size_t)src * 2 + h] + ern);
    den += w;
    acc += w * f[(size_t)src * FD + j];
  }
  float v = acc / fmaxf(den, 1e-9f) + b[j];
  if (do_relu) v = fmaxf(v, 0.f);
  z[(size_t)n * FD + j] = v;
}

__global__ void semw_nodes(const float* __restrict__ z,
                           const float* __restrict__ aw1,
                           const float* __restrict__ ab1,
                           const float* __restrict__ aw2,
                           float* __restrict__ wv) {
  __shared__ float lz[2][FD];
  __shared__ float red[2][4][AH];
  __shared__ float wcol[2][AH];
  const int g = threadIdx.x >> 7;
  const int t = threadIdx.x & 127;
  const int pair = blockIdx.x * 2 + g;
  const int n = pair / RR;
  const int r = pair - n * RR;
  lz[g][t] = z[((size_t)r * NN + n) * FD + t];
  __syncthreads();
  const int col = t & 31;
  const int part = t >> 5;
  float acc = 0.f;
#pragma unroll
  for (int kk = 0; kk < 32; ++kk) {
    const int k = part * 32 + kk;
    acc += lz[g][k] * aw1[(size_t)k * AH + col];
  }
  red[g][part][col] = acc;
  __syncthreads();
  if (part == 0) {
    float s = red[g][0][col] + red[g][1][col] + red[g][2][col] + red[g][3][col];
    wcol[g][col] = tanhf(s + ab1[col]) * aw2[col];
  }
  __syncthreads();
  if (t == 0) {
    float w = 0.f;
#pragma unroll
    for (int c = 0; c < AH; ++c) w += wcol[g][c];
    wv[(size_t)r * NN + n] = w;
  }
}

// ---------------------------------------------------------------------------
extern "C" void kernel_launch(void* const* d_in, const int* in_sizes, int n_in,
                              void* d_out, int out_size, void* d_ws, size_t ws_size,
                              hipStream_t stream) {
  const float* x   = (const float*)d_in[0];
  const int*   edg = (const int*)d_in[1];
  const float* W1  = (const float*)d_in[2];
  const float* al1 = (const float*)d_in[3];
  const float* ar1 = (const float*)d_in[4];
  const float* b1  = (const float*)d_in[5];
  const float* W2  = (const float*)d_in[6];
  const float* al2 = (const float*)d_in[7];
  const float* ar2 = (const float*)d_in[8];
  const float* b2  = (const float*)d_in[9];
  const float* aw1 = (const float*)d_in[10];
  const float* ab1 = (const float*)d_in[11];
  const float* aw2 = (const float*)d_in[12];
  const float* bw1 = (const float*)d_in[13];
  const float* bb1 = (const float*)d_in[14];
  const float* bw2 = (const float*)d_in[15];
  float* out = (float*)d_out;

  const size_t need_big = 67200128;  // gate proven on this ws
  if (ws_size >= need_big) {
    // layout (~62.9 MB of 67.2). bk1|bk2|len2 contiguous -> ONE memset.
    float* bk1    = (float*)d_ws;                    // RR*BKN
    float* bk2    = bk1 + RR * BKN;                  // RR*BKN
    int*   len2   = (int*)(bk2 + RR * BKN);          // RR*NN*2
    float* el     = (float*)(len2 + (size_t)RR * NN * 2);  // RR*NN*2
    float* er     = el + (size_t)RR * NN * 2;        // RR*NN*2
    float* z      = er + (size_t)RR * NN * 2;        // RR*NN*FD fp32
    unsigned short* fb = (unsigned short*)(z + (size_t)RR * NN * FD);  // bf16
    int*   adj    = (int*)(fb + (size_t)RR * NN * FD);  // RR*NN*CAP

    hipMemsetAsync(bk1, 0,
                   (size_t)(2 * RR * BKN) * sizeof(float) +
                       (size_t)RR * NN * 2 * sizeof(int),
                   stream);
    // FAT kernel: layer-1 gemm (1875 blocks) + 2-way sub-bucket scatter
    build_gemm<<<RR * GB2 + (RR * EE + 255) / 256, 256, 0, stream>>>(
        edg, len2, adj, x, W1, al1, ar1, fb, el, er);

    pull_fused<<<RR * (NN / NPB), 256, 0, stream>>>(len2, adj, el, er, fb,
                                                    b1, 1, aw1, ab1, aw2, z, bk1);
    // layer 2 (combine(L1) fused into gemm_mix staging; hmid never stored)
    gemm_mix<<<RR * (NN / BN), 128, 0, stream>>>(z, bk1, W2, al2, ar2, fb, el,
                                                 er);
    pull_fused<<<RR * (NN / NPB), 256, 0, stream>>>(len2, adj, el, er, fb,
                                                    b2, 0, bw1, bb1, bw2, z, bk2);
    combine_bk<<<640, 256, 0, stream>>>(z, bk2, out);
    return;
  }

  // ---------------- fallback: R10 CSR path (46 MB, proven) ----------------
  float* S      = (float*)d_ws;
  float* wv     = S + 16;
  float* el     = wv + (size_t)RR * NN;
  float* er     = el + (size_t)NN * 2;
  float* f      = er + (size_t)NN * 2;
  float* z      = f + (size_t)NN * FD;
  int*   cnt    = (int*)(z + (size_t)RR * NN * FD);
  int*   starts = cnt + RR * NN;
  int*   cursor = starts + RR * NP1;
  int*   csrsrc = cursor + RR * NP1;

  hipMemsetAsync(cnt, 0, (size_t)RR * NN * sizeof(int), stream);
  csr_count<<<(RR * EE + 255) / 256, 256, 0, stream>>>(edg, cnt);
  csr_scan<<<RR, 256, 0, stream>>>(cnt, starts, cursor);
  csr_scatter<<<(RR * EE + 255) / 256, 256, 0, stream>>>(edg, cursor, csrsrc);

  for (int r = 0; r < RR; ++r) {
    gemm_el_er<<<NN / 8, 128, 0, stream>>>(
        x, W1 + (size_t)r * FD * FD, al1 + r * FD, ar1 + r * FD, f, el, er);
    pull_aggr<<<NN, 128, 0, stream>>>(starts + r * NP1, csrsrc + (size_t)r * EE,
                                      el, er, f, b1 + r * FD, 1,
                                      z + (size_t)r * NN * FD);
  }
  semw_nodes<<<NN * RR / 2, 256, 0, stream>>>(z, aw1, ab1, aw2, wv);
  reduce_beta<<<1, 256, 0, stream>>>(wv, S);
  combine_f32<<<(NN * FD + 255) / 256, 256, 0, stream>>>(z, S, out);

  for (int r = 0; r < RR; ++r) {
    gemm_el_er<<<NN / 8, 128, 0, stream>>>(
        out, W2 + (size_t)r * FD * FD, al2 + r * FD, ar2 + r * FD, f, el, er);
    pull_aggr<<<NN, 128, 0, stream>>>(starts + r * NP1, csrsrc + (size_t)r * EE,
                                      el, er, f, b2 + r * FD, 0,
                                      z + (size_t)r * NN * FD);
  }
  semw_nodes<<<NN * RR / 2, 256, 0, stream>>>(z, bw1, bb1, bw2, wv);
  reduce_beta<<<1, 256, 0, stream>>>(wv, S);
  combine_f32<<<(NN * FD + 255) / 256, 256, 0, stream>>>(z, S, out);
}

// Round 19
// 411.473 us; speedup vs baseline: 1.0276x; 1.0276x over previous
//
#include <hip/hip_runtime.h>
#include <hip/hip_bf16.h>

// Established facts (R3-R35): d_in = setup_inputs() dict order; floats fp32;
// edges int32; output fp32 [20000,128]. BEST = R34 408.2us (this kernel).
// PULL AT ROOFLINE ~87.5us x2: invariant under VALU cut (R17), occ +50%
// (R18/R24), conflict fix 55x (R24), uint4 (R25), addr -44% (R27) ->
// ~245MB random line traffic at ~2.8 TB/s fabric floor. SCATTER AT ATOMIC
// ROOFLINE ~95us (inside build_gemm 113us, overlapped with gemm1): invariant
// under 8-way (R28) and 2-way (R35) collision splits -> 960K position
// atomics at per-channel throughput; R35's sub-buckets cost +14us elsewhere
// and were reverted. This round: exact R34 revert (session best).
#define NN 20000
#define RR 3
#define EE 320000
#define FD 128
#define AH 32
#define NP1 (NN + 1)
#define NEG_SLOPE 0.2f
#define BKN 256         // logit buckets per relation
#define NW 4            // waves per block in pull_fused
#define NPW2 8          // nodes per wave
#define NPB (NW * NPW2) // 32 nodes per block
#define LZP (FD + 2)    // padded LDS row: stride 130 (bank-conflict-free)
#define CAP 64          // bucket capacity per (relation, node)
#define GB2 (NN / 32)   // 625 gemm blocks per relation in build_gemm

__device__ __forceinline__ int clamp_idx(int v) {
  v = v < 0 ? 0 : v;
  return v < NN ? v : NN - 1;
}
// leaky_relu(e) == max(e, 0.2*e) for all e (0.2e > e when e < 0)
__device__ __forceinline__ float leaky_exp(float e) {
  return __expf(fmaxf(e, NEG_SLOPE * e));
}
__device__ __forceinline__ float bf2f(unsigned short u) {
  union { unsigned int i; float f; } c;
  c.i = ((unsigned int)u) << 16;
  return c.f;
}
// fp32 -> bf16 with round-to-nearest-even (values are finite, |v| ~ O(1))
__device__ __forceinline__ unsigned short f2bf(float v) {
  union { float f; unsigned int i; } c;
  c.f = v;
  const unsigned int u = c.i;
  return (unsigned short)((u + 0x7fffu + ((u >> 16) & 1u)) >> 16);
}

// ---------------------------------------------------------------------------
// build_gemm: FAT kernel. Blocks [0, RR*GB2) run layer-1 gemm (4 waves x 8
// nodes = 32 nodes/block; per-wave math identical to R31's proven version ->
// bit-identical fb/el/er). Blocks [RR*GB2, +3750) run bucket_scatter
// (byte-identical body). Roles touch disjoint data; no inter-role sync.
// Scatter's atomic/scatter latency overlaps gemm's VALU work.
// ---------------------------------------------------------------------------
__global__ void __launch_bounds__(256, 2) build_gemm(
    const int* __restrict__ edg,
    int* __restrict__ len,
    int* __restrict__ adj,
    const float* __restrict__ hin,            // [N,128]
    const float* __restrict__ W,              // [3,128,128]
    const float* __restrict__ al,             // [3,128]
    const float* __restrict__ ar,             // [3,128]
    unsigned short* __restrict__ fb,          // [3,N,128] bf16
    float* __restrict__ el,                   // [3,N,2]
    float* __restrict__ er) {
  __shared__ float lh[32 * FD];  // 16 KB (gemm role only)
  const int gemmBlocks = RR * GB2;  // 1875
  const int t = threadIdx.x;

  if (blockIdx.x >= gemmBlocks) {
    // ---------------- scatter role (byte-identical to bucket_scatter) ------
    const int idx = (blockIdx.x - gemmBlocks) * 256 + t;
    if (idx >= RR * EE) return;
    const int r = idx / EE, k = idx - r * EE;
    const int src = clamp_idx(edg[(size_t)r * 2 * EE + k]);
    const int dst = clamp_idx(edg[(size_t)r * 2 * EE + EE + k]);
    const int pos = atomicAdd(&len[r * NN + dst], 1);
    if (pos < CAP) adj[((size_t)r * NN + dst) * CAP + pos] = src;
    return;
  }

  // ---------------- gemm role (R31 per-wave math, 4 waves) -----------------
  const int r = blockIdx.x / GB2;
  const int n0 = (blockIdx.x - r * GB2) * 32;
  const int wv = t >> 6;       // wave 0..3
  const int j = t & 63;        // lane

  {
    const float4* s4 = (const float4*)&hin[(size_t)n0 * FD];
    float4* d4 = (float4*)lh;
#pragma unroll
    for (int p = 0; p < 4; ++p) d4[t + 256 * p] = s4[t + 256 * p];
  }
  __syncthreads();

  const float* Wr = W + (size_t)r * FD * FD;
  const float* lhw = lh + wv * 8 * FD;  // this wave's 8 nodes
  float acc0[8], acc1[8];
#pragma unroll
  for (int i = 0; i < 8; ++i) { acc0[i] = 0.f; acc1[i] = 0.f; }

  for (int k4 = 0; k4 < FD; k4 += 4) {
    const float wa0 = Wr[(size_t)(k4 + 0) * FD + j];
    const float wb0 = Wr[(size_t)(k4 + 0) * FD + j + 64];
    const float wa1 = Wr[(size_t)(k4 + 1) * FD + j];
    const float wb1 = Wr[(size_t)(k4 + 1) * FD + j + 64];
    const float wa2 = Wr[(size_t)(k4 + 2) * FD + j];
    const float wb2 = Wr[(size_t)(k4 + 2) * FD + j + 64];
    const float wa3 = Wr[(size_t)(k4 + 3) * FD + j];
    const float wb3 = Wr[(size_t)(k4 + 3) * FD + j + 64];
#pragma unroll
    for (int i = 0; i < 8; ++i) {
      const float4 h4 = *(const float4*)&lhw[i * FD + k4];
      acc0[i] = fmaf(h4.x, wa0, fmaf(h4.y, wa1, fmaf(h4.z, wa2, fmaf(h4.w, wa3, acc0[i]))));
      acc1[i] = fmaf(h4.x, wb0, fmaf(h4.y, wb1, fmaf(h4.z, wb2, fmaf(h4.w, wb3, acc1[i]))));
    }
  }

  const float al0 = al[r * FD + j];
  const float al1v = al[r * FD + j + 64];
  const float ar0 = ar[r * FD + j];
  const float ar1v = ar[r * FD + j + 64];

#pragma unroll
  for (int i = 0; i < 8; ++i) {
    const int node = n0 + wv * 8 + i;
    const size_t row = ((size_t)r * NN + node) * FD;
    fb[row + j] = f2bf(acc0[i]);
    fb[row + j + 64] = f2bf(acc1[i]);
    float e0 = acc0[i] * al0;
    float e1 = acc1[i] * al1v;
    float u0 = acc0[i] * ar0;
    float u1 = acc1[i] * ar1v;
#pragma unroll
    for (int off = 32; off > 0; off >>= 1) {
      e0 += __shfl_down(e0, off, 64);
      e1 += __shfl_down(e1, off, 64);
      u0 += __shfl_down(u0, off, 64);
      u1 += __shfl_down(u1, off, 64);
    }
    if (j == 0) {
      const size_t base = ((size_t)r * NN + node) * 2;
      el[base + 0] = e0;
      el[base + 1] = e1;
      er[base + 0] = u0;
      er[base + 1] = u1;
    }
  }
}

// ---------------------------------------------------------------------------
// gemm_mix (R33-proven): layer-2 gemm with L1 combine fused into staging.
// ---------------------------------------------------------------------------
#define BN 16
__global__ void __launch_bounds__(128, 2) gemm_mix(
    const float* __restrict__ z,              // [3,N,128] layer-1 outputs
    const float* __restrict__ bk,             // [3,BKN] logit buckets
    const float* __restrict__ W,              // [3,128,128]
    const float* __restrict__ al,             // [3,128]
    const float* __restrict__ ar,             // [3,128]
    unsigned short* __restrict__ fb,          // [3,N,128] bf16
    float* __restrict__ el,                   // [3,N,2]
    float* __restrict__ er) {
  __shared__ float lh[BN * FD];  // 8 KB
  __shared__ float red[128];
  __shared__ float betas[4];
  const int blocksPerRel = NN / BN;  // 1250
  const int r = blockIdx.x / blocksPerRel;
  const int n0 = (blockIdx.x % blocksPerRel) * BN;
  const int t = threadIdx.x;   // 0..127
  const int wv = t >> 6;       // wave 0/1
  const int j = t & 63;        // lane

  // ---- beta from buckets (matches combine_bk's reduction + softmax) ----
  float tot[RR];
#pragma unroll
  for (int r2 = 0; r2 < RR; ++r2) {
    red[t] = bk[r2 * BKN + t] + bk[r2 * BKN + t + 128];
    __syncthreads();
    for (int off = 64; off > 0; off >>= 1) {
      if (t < off) red[t] += red[t + off];
      __syncthreads();
    }
    tot[r2] = red[0];
    __syncthreads();
  }
  if (t == 0) {
    const float w0 = tot[0] * (1.f / NN);
    const float w1 = tot[1] * (1.f / NN);
    const float w2 = tot[2] * (1.f / NN);
    const float mx = fmaxf(w0, fmaxf(w1, w2));
    const float e0 = __expf(w0 - mx), e1 = __expf(w1 - mx), e2 = __expf(w2 - mx);
    const float inv = 1.f / (e0 + e1 + e2);
    betas[0] = e0 * inv; betas[1] = e1 * inv; betas[2] = e2 * inv;
  }
  __syncthreads();
  const float b0 = betas[0], b1 = betas[1], b2 = betas[2];

  // ---- stage mixed hmid tile: 16 nodes x 128 cols = 512 float4 ----
  {
    const float4* z40 = (const float4*)&z[(size_t)n0 * FD];
    const float4* z41 = (const float4*)&z[(size_t)NN * FD + (size_t)n0 * FD];
    const float4* z42 = (const float4*)&z[2 * (size_t)NN * FD + (size_t)n0 * FD];
    float4* d4 = (float4*)lh;
#pragma unroll
    for (int p = 0; p < 4; ++p) {
      const int m = t + 128 * p;
      const float4 a = z40[m];
      const float4 bq = z41[m];
      const float4 c = z42[m];
      float4 o;
      o.x = b0 * a.x + b1 * bq.x + b2 * c.x;
      o.y = b0 * a.y + b1 * bq.y + b2 * c.y;
      o.z = b0 * a.z + b1 * bq.z + b2 * c.z;
      o.w = b0 * a.w + b1 * bq.w + b2 * c.w;
      d4[m] = o;
    }
  }
  __syncthreads();

  const float* Wr = W + (size_t)r * FD * FD;
  const float* lhw = lh + wv * 8 * FD;  // this wave's 8 nodes
  float acc0[8], acc1[8];
#pragma unroll
  for (int i = 0; i < 8; ++i) { acc0[i] = 0.f; acc1[i] = 0.f; }

  for (int k4 = 0; k4 < FD; k4 += 4) {
    const float wa0 = Wr[(size_t)(k4 + 0) * FD + j];
    const float wb0 = Wr[(size_t)(k4 + 0) * FD + j + 64];
    const float wa1 = Wr[(size_t)(k4 + 1) * FD + j];
    const float wb1 = Wr[(size_t)(k4 + 1) * FD + j + 64];
    const float wa2 = Wr[(size_t)(k4 + 2) * FD + j];
    const float wb2 = Wr[(size_t)(k4 + 2) * FD + j + 64];
    const float wa3 = Wr[(size_t)(k4 + 3) * FD + j];
    const float wb3 = Wr[(size_t)(k4 + 3) * FD + j + 64];
#pragma unroll
    for (int i = 0; i < 8; ++i) {
      const float4 h4 = *(const float4*)&lhw[i * FD + k4];
      acc0[i] = fmaf(h4.x, wa0, fmaf(h4.y, wa1, fmaf(h4.z, wa2, fmaf(h4.w, wa3, acc0[i]))));
      acc1[i] = fmaf(h4.x, wb0, fmaf(h4.y, wb1, fmaf(h4.z, wb2, fmaf(h4.w, wb3, acc1[i]))));
    }
  }

  const float al0 = al[r * FD + j];
  const float al1v = al[r * FD + j + 64];
  const float ar0 = ar[r * FD + j];
  const float ar1v = ar[r * FD + j + 64];

#pragma unroll
  for (int i = 0; i < 8; ++i) {
    const int node = n0 + wv * 8 + i;
    const size_t row = ((size_t)r * NN + node) * FD;
    fb[row + j] = f2bf(acc0[i]);
    fb[row + j + 64] = f2bf(acc1[i]);
    float e0 = acc0[i] * al0;
    float e1 = acc1[i] * al1v;
    float u0 = acc0[i] * ar0;
    float u1 = acc1[i] * ar1v;
#pragma unroll
    for (int off = 32; off > 0; off >>= 1) {
      e0 += __shfl_down(e0, off, 64);
      e1 += __shfl_down(e1, off, 64);
      u0 += __shfl_down(u0, off, 64);
      u1 += __shfl_down(u1, off, 64);
    }
    if (j == 0) {
      const size_t base = ((size_t)r * NN + node) * 2;
      el[base + 0] = e0;
      el[base + 1] = e1;
      er[base + 0] = u0;
      er[base + 1] = u1;
    }
  }
}

// ---------------------------------------------------------------------------
// pull_fused v5 (R30-R34-proven, byte-identical): block = 4 waves = 32 nodes.
// Lane l owns (node g=l&7, head, quad); adj/el2 loads exec-masked to lanes
// 0-7 + __shfl broadcast; fb gathered as 2 x uint4 per edge; lz[32][130]
// pad; bucket-atomic logits. Segment: s0=node*CAP, deg=min(len,CAP).
// ---------------------------------------------------------------------------
__global__ void __launch_bounds__(256, 4) pull_fused(
    const int* __restrict__ len,      // [3,NN]
    const int* __restrict__ adj,      // [3,NN,CAP]
    const float* __restrict__ el,     // [3,N,2]
    const float* __restrict__ er,
    const unsigned short* __restrict__ fb,  // [3,N,128] bf16
    const float* __restrict__ b,      // [3,128]
    int do_relu,
    const float* __restrict__ aw1,    // [128,32]
    const float* __restrict__ ab1,    // [32]
    const float* __restrict__ aw2,    // [32]
    float* __restrict__ z,            // [3,N,128]
    float* __restrict__ bucket) {     // [3,BKN]
  __shared__ float lz[NPB][LZP];  // 32 x 130 floats = 16.6 KB
  const int t = threadIdx.x;
  const int wave = t >> 6;
  const int l = t & 63;
  const int g = l & 7;                     // node group within wave
  const int bpr = NN / NPB;  // 625
  const int r = blockIdx.x / bpr;
  const int nb = (blockIdx.x - r * bpr) * NPB;
  const int widx = wave * NPW2 + g;        // node index within block 0..31
  const int node = nb + widx;
  const int h = (l >> 3) & 1;
  const int q = l >> 4;                    // 0..3
  const int rn = r * NN + node;
  const int* ln = len + r * NN;
  const int* ad = adj + (size_t)r * NN * CAP;
  const float2* el2 = (const float2*)(el + (size_t)r * NN * 2);
  const unsigned int* fru = (const unsigned int*)(fb + (size_t)r * NN * FD);
  const int deg = min(ln[node], CAP);
  const size_t s0 = (size_t)node * CAP;
  const float ern = er[(size_t)rn * 2 + h];

  float2 acc[8];
#pragma unroll
  for (int i = 0; i < 8; ++i) acc[i] = make_float2(0.f, 0.f);
  float den = 0.f;

  // max degree over the 8 nodes of this wave (node id depends only on l&7)
  int md = deg;
  md = max(md, __shfl_xor(md, 1, 64));
  md = max(md, __shfl_xor(md, 2, 64));
  md = max(md, __shfl_xor(md, 4, 64));

  for (int k = 0; k < md; ++k) {
    // lanes 0..7 load adj + el2 for their group (8 addresses instead of 64)
    int srcv = 0;
    float2 e2v = make_float2(0.f, 0.f);
    if (l < 8 && k < deg) {           // lane l<8 has g==l -> own s0/deg
      srcv = ad[s0 + k];
      e2v = el2[srcv];
    }
    const int src = __shfl(srcv, g, 64);
    const float ex = __shfl(e2v.x, g, 64);
    const float ey = __shfl(e2v.y, g, 64);
    if (k < deg) {
      const float w = leaky_exp((h ? ey : ex) + ern);
      den += w;
      const uint4* frow = (const uint4*)(fru + (src << 6) + (h << 5) + (q << 3));
      const uint4 fa = frow[0];
      const uint4 fbv = frow[1];
      acc[0].x += w * bf2f((unsigned short)(fa.x & 0xffff));
      acc[0].y += w * bf2f((unsigned short)(fa.x >> 16));
      acc[1].x += w * bf2f((unsigned short)(fa.y & 0xffff));
      acc[1].y += w * bf2f((unsigned short)(fa.y >> 16));
      acc[2].x += w * bf2f((unsigned short)(fa.z & 0xffff));
      acc[2].y += w * bf2f((unsigned short)(fa.z >> 16));
      acc[3].x += w * bf2f((unsigned short)(fa.w & 0xffff));
      acc[3].y += w * bf2f((unsigned short)(fa.w >> 16));
      acc[4].x += w * bf2f((unsigned short)(fbv.x & 0xffff));
      acc[4].y += w * bf2f((unsigned short)(fbv.x >> 16));
      acc[5].x += w * bf2f((unsigned short)(fbv.y & 0xffff));
      acc[5].y += w * bf2f((unsigned short)(fbv.y >> 16));
      acc[6].x += w * bf2f((unsigned short)(fbv.z & 0xffff));
      acc[6].y += w * bf2f((unsigned short)(fbv.z >> 16));
      acc[7].x += w * bf2f((unsigned short)(fbv.w & 0xffff));
      acc[7].y += w * bf2f((unsigned short)(fbv.w >> 16));
    }
  }

  const float inv = 1.f / fmaxf(den, 1e-9f);
  const int cbase = h * 64 + q * 16;
  const float* bb = b + r * FD + cbase;
  float* zr = z + (size_t)rn * FD + cbase;
#pragma unroll
  for (int cp = 0; cp < 8; ++cp) {
    float vx = acc[cp].x * inv + bb[2 * cp];
    float vy = acc[cp].y * inv + bb[2 * cp + 1];
    if (do_relu) { vx = fmaxf(vx, 0.f); vy = fmaxf(vy, 0.f); }
    ((float2*)zr)[cp] = make_float2(vx, vy);
    lz[widx][cbase + 2 * cp] = vx;
    lz[widx][cbase + 2 * cp + 1] = vy;
  }
  __syncthreads();

  // ---- fused semantic-attention logit for the block's 32 nodes ----
  // 8 threads per node; thread i owns cols i, i+8, i+16, i+24.
  const int mnode = t >> 3;   // 0..31
  const int i = t & 7;
  float a0 = ab1[i], a1 = ab1[i + 8], a2 = ab1[i + 16], a3 = ab1[i + 24];
  const float* aw1i = aw1 + i;
  for (int k = 0; k < FD; ++k) {
    const float zv = lz[mnode][k];
    const float* a = aw1i + (size_t)k * AH;
    a0 = fmaf(zv, a[0], a0);
    a1 = fmaf(zv, a[8], a1);
    a2 = fmaf(zv, a[16], a2);
    a3 = fmaf(zv, a[24], a3);
  }
  float part = tanhf(a0) * aw2[i] + tanhf(a1) * aw2[i + 8] +
               tanhf(a2) * aw2[i + 16] + tanhf(a3) * aw2[i + 24];
  part += __shfl_down(part, 4, 64);
  part += __shfl_down(part, 2, 64);
  part += __shfl_down(part, 1, 64);
  if (i == 0)
    atomicAdd(&bucket[r * BKN + ((nb + mnode) & (BKN - 1))], part);
}

// grid-strided combine; reduces the 3*BKN logit buckets in-block and applies
// the beta softmax inline (R19/R24-proven)
__global__ void combine_bk(const float* __restrict__ z,
                           const float* __restrict__ bk,  // [3,BKN]
                           float* __restrict__ out) {
  __shared__ float p[256];
  __shared__ float beta[3];
  const int t = threadIdx.x;
  float tot[RR];
#pragma unroll
  for (int r = 0; r < RR; ++r) {
    p[t] = bk[r * BKN + t];
    __syncthreads();
    for (int off = 128; off > 0; off >>= 1) {
      if (t < off) p[t] += p[t + off];
      __syncthreads();
    }
    tot[r] = p[0];
    __syncthreads();
  }
  if (t == 0) {
    const float w0 = tot[0] * (1.f / NN);
    const float w1 = tot[1] * (1.f / NN);
    const float w2 = tot[2] * (1.f / NN);
    const float mx = fmaxf(w0, fmaxf(w1, w2));
    const float e0 = __expf(w0 - mx), e1 = __expf(w1 - mx), e2 = __expf(w2 - mx);
    const float inv = 1.f / (e0 + e1 + e2);
    beta[0] = e0 * inv; beta[1] = e1 * inv; beta[2] = e2 * inv;
  }
  __syncthreads();
  const float b0 = beta[0], b1 = beta[1], b2 = beta[2];
  for (int idx = blockIdx.x * 256 + t; idx < NN * FD; idx += gridDim.x * 256)
    out[idx] = b0 * z[idx] + b1 * z[(size_t)NN * FD + idx] +
               b2 * z[2 * (size_t)NN * FD + idx];
}

// ------------------- fallback kernels (R10 CSR path, proven) ----------------
__global__ void csr_count(const int* __restrict__ edg, int* __restrict__ cnt) {
  const int idx = blockIdx.x * blockDim.x + threadIdx.x;
  if (idx >= RR * EE) return;
  const int r = idx / EE, k = idx - r * EE;
  const int dst = clamp_idx(edg[(size_t)r * 2 * EE + EE + k]);
  atomicAdd(&cnt[r * NN + dst], 1);
}

__global__ void csr_scan(const int* __restrict__ cnt, int* __restrict__ starts,
                         int* __restrict__ cursor) {
  __shared__ int part[256];
  const int r = blockIdx.x, t = threadIdx.x;
  const int CH = (NN + 255) / 256;  // 79
  const int lo = t * CH, hi = min(lo + CH, NN);
  int s = 0;
  for (int i = lo; i < hi; ++i) s += cnt[r * NN + i];
  part[t] = s;
  __syncthreads();
  for (int off = 1; off < 256; off <<= 1) {
    const int x = part[t];
    const int y = (t >= off) ? part[t - off] : 0;
    __syncthreads();
    part[t] = x + y;
    __syncthreads();
  }
  int run = (t == 0) ? 0 : part[t - 1];
  for (int i = lo; i < hi; ++i) {
    starts[r * NP1 + i] = run;
    cursor[r * NP1 + i] = run;
    run += cnt[r * NN + i];
  }
  if (t == 255) starts[r * NP1 + NN] = run;
}

__global__ void csr_scatter(const int* __restrict__ edg, int* __restrict__ cursor,
                            int* __restrict__ csrsrc) {
  const int idx = blockIdx.x * blockDim.x + threadIdx.x;
  if (idx >= RR * EE) return;
  const int r = idx / EE, k = idx - r * EE;
  const int src = clamp_idx(edg[(size_t)r * 2 * EE + k]);
  const int dst = clamp_idx(edg[(size_t)r * 2 * EE + EE + k]);
  const int pos = atomicAdd(&cursor[r * NP1 + dst], 1);
  csrsrc[(size_t)r * EE + pos] = src;
}

__global__ void reduce_beta(const float* __restrict__ wv, float* __restrict__ S) {
  __shared__ float p[256];
  const int t = threadIdx.x;
  float tot[RR];
  for (int r = 0; r < RR; ++r) {
    float s = 0.f;
    for (int n = t; n < NN; n += 256) s += wv[(size_t)r * NN + n];
    p[t] = s;
    __syncthreads();
    for (int off = 128; off > 0; off >>= 1) {
      if (t < off) p[t] += p[t + off];
      __syncthreads();
    }
    tot[r] = p[0];
    __syncthreads();
  }
  if (t == 0) {
    S[0] = tot[0]; S[1] = tot[1]; S[2] = tot[2];
    float w0 = tot[0] / (float)NN, w1 = tot[1] / (float)NN, w2 = tot[2] / (float)NN;
    float mx = fmaxf(w0, fmaxf(w1, w2));
    float e0 = __expf(w0 - mx), e1 = __expf(w1 - mx), e2 = __expf(w2 - mx);
    float inv = 1.f / (e0 + e1 + e2);
    S[4] = e0 * inv; S[5] = e1 * inv; S[6] = e2 * inv;
  }
}

__global__ void combine_f32(const float* __restrict__ z,
                            const float* __restrict__ S,
                            float* __restrict__ out) {
  const int idx = blockIdx.x * blockDim.x + threadIdx.x;
  if (idx >= NN * FD) return;
  out[idx] = S[4] * z[idx] + S[5] * z[(size_t)NN * FD + idx] +
             S[6] * z[2 * (size_t)NN * FD + idx];
}

__global__ void gemm_el_er(const float* __restrict__ hin,
                           const float* __restrict__ W,
                           const float* __restrict__ al,
                           const float* __restrict__ ar,
                           float* __restrict__ f,
                           float* __restrict__ el,
                           float* __restrict__ er) {
  const int B8 = 8;
  __shared__ float lh[B8 * FD];
  const int j = threadIdx.x;
  const int n0 = blockIdx.x * B8;
#pragma unroll
  for (int i = 0; i < B8; ++i)
    lh[i * FD + j] = hin[(size_t)(n0 + i) * FD + j];
  __syncthreads();
  float acc[B8];
#pragma unroll
  for (int i = 0; i < B8; ++i) acc[i] = 0.f;
  for (int k = 0; k < FD; ++k) {
    const float w = W[(size_t)k * FD + j];
#pragma unroll
    for (int i = 0; i < B8; ++i) acc[i] += lh[i * FD + k] * w;
  }
  const float alv = al[j];
  const float arv = ar[j];
#pragma unroll
  for (int i = 0; i < B8; ++i) f[(size_t)(n0 + i) * FD + j] = acc[i];
  __syncthreads();
#pragma unroll
  for (int i = 0; i < B8; ++i) lh[i * FD + j] = acc[i] * alv;
  __syncthreads();
  if (j < B8 * 2) {
    const int i = j >> 1, h = j & 1;
    const float* p = &lh[i * FD + h * 64];
    float s = 0.f;
    for (int d = 0; d < 64; ++d) s += p[d];
    el[(size_t)(n0 + i) * 2 + h] = s;
  }
  __syncthreads();
#pragma unroll
  for (int i = 0; i < B8; ++i) lh[i * FD + j] = acc[i] * arv;
  __syncthreads();
  if (j < B8 * 2) {
    const int i = j >> 1, h = j & 1;
    const float* p = &lh[i * FD + h * 64];
    float s = 0.f;
    for (int d = 0; d < 64; ++d) s += p[d];
    er[(size_t)(n0 + i) * 2 + h] = s;
  }
}

__global__ void pull_aggr(const int* __restrict__ starts,
                          const int* __restrict__ csrsrc,
                          const float* __restrict__ el,
                          const float* __restrict__ er,
                          const float* __restrict__ f,
                          const float* __restrict__ b,
                          int do_relu,
                          float* __restrict__ z) {
  const int n = blockIdx.x;
  const int j = threadIdx.x;
  const int h = j >> 6;
  const int s0 = starts[n], s1 = starts[n + 1];
  const float ern = er[(size_t)n * 2 + h];
  float acc = 0.f, den = 0.f;
  for (int p = s0; p < s1; ++p) {
    const int src = csrsrc[p];
    const float w = leaky_exp(el[(size_t)src * 2 + h] + ern);
    den += w;
    acc += w * f[(size_t)src * FD + j];
  }
  float v = acc / fmaxf(den, 1e-9f) + b[j];
  if (do_relu) v = fmaxf(v, 0.f);
  z[(size_t)n * FD + j] = v;
}

__global__ void semw_nodes(const float* __restrict__ z,
                           const float* __restrict__ aw1,
                           const float* __restrict__ ab1,
                           const float* __restrict__ aw2,
                           float* __restrict__ wv) {
  __shared__ float lz[2][FD];
  __shared__ float red[2][4][AH];
  __shared__ float wcol[2][AH];
  const int g = threadIdx.x >> 7;
  const int t = threadIdx.x & 127;
  const int pair = blockIdx.x * 2 + g;
  const int n = pair / RR;
  const int r = pair - n * RR;
  lz[g][t] = z[((size_t)r * NN + n) * FD + t];
  __syncthreads();
  const int col = t & 31;
  const int part = t >> 5;
  float acc = 0.f;
#pragma unroll
  for (int kk = 0; kk < 32; ++kk) {
    const int k = part * 32 + kk;
    acc += lz[g][k] * aw1[(size_t)k * AH + col];
  }
  red[g][part][col] = acc;
  __syncthreads();
  if (part == 0) {
    float s = red[g][0][col] + red[g][1][col] + red[g][2][col] + red[g][3][col];
    wcol[g][col] = tanhf(s + ab1[col]) * aw2[col];
  }
  __syncthreads();
  if (t == 0) {
    float w = 0.f;
#pragma unroll
    for (int c = 0; c < AH; ++c) w += wcol[g][c];
    wv[(size_t)r * NN + n] = w;
  }
}

// ---------------------------------------------------------------------------
extern "C" void kernel_launch(void* const* d_in, const int* in_sizes, int n_in,
                              void* d_out, int out_size, void* d_ws, size_t ws_size,
                              hipStream_t stream) {
  const float* x   = (const float*)d_in[0];
  const int*   edg = (const int*)d_in[1];
  const float* W1  = (const float*)d_in[2];
  const float* al1 = (const float*)d_in[3];
  const float* ar1 = (const float*)d_in[4];
  const float* b1  = (const float*)d_in[5];
  const float* W2  = (const float*)d_in[6];
  const float* al2 = (const float*)d_in[7];
  const float* ar2 = (const float*)d_in[8];
  const float* b2  = (const float*)d_in[9];
  const float* aw1 = (const float*)d_in[10];
  const float* ab1 = (const float*)d_in[11];
  const float* aw2 = (const float*)d_in[12];
  const float* bw1 = (const float*)d_in[13];
  const float* bb1 = (const float*)d_in[14];
  const float* bw2 = (const float*)d_in[15];
  float* out = (float*)d_out;

  const size_t need_big = 67200128;  // gate proven on this ws
  if (ws_size >= need_big) {
    // layout (~62.6 MB of 67.2). bk1|bk2|len contiguous -> ONE memset.
    float* bk1    = (float*)d_ws;                    // RR*BKN
    float* bk2    = bk1 + RR * BKN;                  // RR*BKN
    int*   len    = (int*)(bk2 + RR * BKN);          // RR*NN
    float* el     = (float*)(len + RR * NN);         // RR*NN*2
    float* er     = el + (size_t)RR * NN * 2;        // RR*NN*2
    float* z      = er + (size_t)RR * NN * 2;        // RR*NN*FD fp32
    unsigned short* fb = (unsigned short*)(z + (size_t)RR * NN * FD);  // bf16
    int*   adj    = (int*)(fb + (size_t)RR * NN * FD);  // RR*NN*CAP

    hipMemsetAsync(bk1, 0,
                   (size_t)(2 * RR * BKN) * sizeof(float) +
                       (size_t)RR * NN * sizeof(int),
                   stream);
    // FAT kernel: layer-1 gemm (1875 blocks) + bucket scatter (3750 blocks)
    build_gemm<<<RR * GB2 + (RR * EE + 255) / 256, 256, 0, stream>>>(
        edg, len, adj, x, W1, al1, ar1, fb, el, er);

    pull_fused<<<RR * (NN / NPB), 256, 0, stream>>>(len, adj, el, er, fb,
                                                    b1, 1, aw1, ab1, aw2, z, bk1);
    // layer 2 (combine(L1) fused into gemm_mix staging; hmid never stored)
    gemm_mix<<<RR * (NN / BN), 128, 0, stream>>>(z, bk1, W2, al2, ar2, fb, el,
                                                 er);
    pull_fused<<<RR * (NN / NPB), 256, 0, stream>>>(len, adj, el, er, fb,
                                                    b2, 0, bw1, bb1, bw2, z, bk2);
    combine_bk<<<640, 256, 0, stream>>>(z, bk2, out);
    return;
  }

  // ---------------- fallback: R10 CSR path (46 MB, proven) ----------------
  float* S      = (float*)d_ws;
  float* wv     = S + 16;
  float* el     = wv + (size_t)RR * NN;
  float* er     = el + (size_t)NN * 2;
  float* f      = er + (size_t)NN * 2;
  float* z      = f + (size_t)NN * FD;
  int*   cnt    = (int*)(z + (size_t)RR * NN * FD);
  int*   starts = cnt + RR * NN;
  int*   cursor = starts + RR * NP1;
  int*   csrsrc = cursor + RR * NP1;

  hipMemsetAsync(cnt, 0, (size_t)RR * NN * sizeof(int), stream);
  csr_count<<<(RR * EE + 255) / 256, 256, 0, stream>>>(edg, cnt);
  csr_scan<<<RR, 256, 0, stream>>>(cnt, starts, cursor);
  csr_scatter<<<(RR * EE + 255) / 256, 256, 0, stream>>>(edg, cursor, csrsrc);

  for (int r = 0; r < RR; ++r) {
    gemm_el_er<<<NN / 8, 128, 0, stream>>>(
        x, W1 + (size_t)r * FD * FD, al1 + r * FD, ar1 + r * FD, f, el, er);
    pull_aggr<<<NN, 128, 0, stream>>>(starts + r * NP1, csrsrc + (size_t)r * EE,
                                      el, er, f, b1 + r * FD, 1,
                                      z + (size_t)r * NN * FD);
  }
  semw_nodes<<<NN * RR / 2, 256, 0, stream>>>(z, aw1, ab1, aw2, wv);
  reduce_beta<<<1, 256, 0, stream>>>(wv, S);
  combine_f32<<<(NN * FD + 255) / 256, 256, 0, stream>>>(z, S, out);

  for (int r = 0; r < RR; ++r) {
    gemm_el_er<<<NN / 8, 128, 0, stream>>>(
        out, W2 + (size_t)r * FD * FD, al2 + r * FD, ar2 + r * FD, f, el, er);
    pull_aggr<<<NN, 128, 0, stream>>>(starts + r * NP1, csrsrc + (size_t)r * EE,
                                      el, er, f, b2 + r * FD, 0,
                                      z + (size_t)r * NN * FD);
  }
  semw_nodes<<<NN * RR / 2, 256, 0, stream>>>(z, bw1, bb1, bw2, wv);
  reduce_beta<<<1, 256, 0, stream>>>(wv, S);
  combine_f32<<<(NN * FD + 255) / 256, 256, 0, stream>>>(z, S, out);
}